// Round 20
// baseline (60.111 us; speedup 1.0000x reference)
//
#include <hip/hip_runtime.h>

#define N_NODES 100000
#define DIM 64
#define N_TILES (N_NODES / 16)   // 6250 row-tiles of 16

#define BSHIFT 7
#define BN 128                         // nodes per bucket
#define NB ((N_NODES + BN - 1) / BN)   // 782 buckets
#define BC 2048                        // bucket capacity (mean 1598, ~11 sigma)

#define NP 256                         // partition blocks (even)
#define NT 256                         // transform blocks (odd)
#define CHUNK_P 4928                   // >= per = ceil(E/NP) rounded to x4

using bf16x8 = __attribute__((ext_vector_type(8))) short;
using f32x4  = __attribute__((ext_vector_type(4))) float;

__device__ __forceinline__ unsigned short f2bf(float f) {
    unsigned u = __float_as_uint(f);
    unsigned r = u + 0x7FFFu + ((u >> 16) & 1u);
    return (unsigned short)(r >> 16);
}

union PrepShared {
    struct {
        unsigned vals[CHUNK_P];        // 19.7 KB packed entries
        unsigned srt[CHUNK_P];         // 19.7 KB bucket-sorted entries
        unsigned short bkt[CHUNK_P];   // 9.9 KB bucket ids
        int hist[NB];
        int offs[NB];
        int cur[NB];
    } p;                               // ~58.7 KB
    ushort t[16 * 16 * 72];            // 36.9 KB
};                                      // 2 blocks/CU: 117 KB <= 160 KB

// ---- pass 1: even blocks = partition (block-local counting sort,
// ----         dense sequential writeout + per-block offset table),
// ----         odd blocks = transform (MFMA) ----------------------------
__global__ __launch_bounds__(1024, 2)
void prep_kernel(const float* __restrict__ x,
                 const float* __restrict__ W,
                 const int* __restrict__ edge_src,
                 const int* __restrict__ edge_dst,
                 int* __restrict__ blk_offs,      // [NP][NB+1]
                 unsigned* __restrict__ bsorted,  // [NP][per4]
                 ushort* __restrict__ y, int E, int per4) {
    __shared__ PrepShared sh;
    const int tid = threadIdx.x;

    if ((blockIdx.x & 1) == 0) {
        // ---------- partition -------------------------------------------
        const int pid = blockIdx.x >> 1;
        const int e0 = pid * per4;
        int m = E - e0;
        if (m < 0) m = 0;
        if (m > per4) m = per4;

        for (int i = tid; i < NB; i += 1024) sh.p.hist[i] = 0;
        __syncthreads();

        // load + pack + histogram (int4: 4 edges/thread/iter)
        {
            const int G = m >> 2;
            const int4* __restrict__ d4p = (const int4*)(edge_dst + e0);
            const int4* __restrict__ s4p = (const int4*)(edge_src + e0);
            for (int g = tid; g < G; g += 1024) {
                int4 d = d4p[g];
                int4 s = s4p[g];
                uint4 v;
                v.x = ((unsigned)(d.x & (BN - 1)) << 20) | (unsigned)s.x;
                v.y = ((unsigned)(d.y & (BN - 1)) << 20) | (unsigned)s.y;
                v.z = ((unsigned)(d.z & (BN - 1)) << 20) | (unsigned)s.z;
                v.w = ((unsigned)(d.w & (BN - 1)) << 20) | (unsigned)s.w;
                *(uint4*)(sh.p.vals + (g << 2)) = v;
                ushort4 bk;
                bk.x = (unsigned short)(d.x >> BSHIFT);
                bk.y = (unsigned short)(d.y >> BSHIFT);
                bk.z = (unsigned short)(d.z >> BSHIFT);
                bk.w = (unsigned short)(d.w >> BSHIFT);
                *(ushort4*)(sh.p.bkt + (g << 2)) = bk;
                atomicAdd(&sh.p.hist[bk.x], 1);
                atomicAdd(&sh.p.hist[bk.y], 1);
                atomicAdd(&sh.p.hist[bk.z], 1);
                atomicAdd(&sh.p.hist[bk.w], 1);
            }
            for (int i = (G << 2) + tid; i < m; i += 1024) {
                int d = edge_dst[e0 + i];
                int s = edge_src[e0 + i];
                int b = d >> BSHIFT;
                sh.p.vals[i] = ((unsigned)(d & (BN - 1)) << 20) | (unsigned)s;
                sh.p.bkt[i] = (unsigned short)b;
                atomicAdd(&sh.p.hist[b], 1);
            }
        }
        __syncthreads();

        // exclusive scan of hist over NB (Hillis-Steele, 10 rounds)
        if (tid < NB) sh.p.offs[tid] = sh.p.hist[tid];
        __syncthreads();
        for (int o = 1; o < NB; o <<= 1) {
            int t = 0;
            if (tid < NB && tid >= o) t = sh.p.offs[tid - o];
            __syncthreads();
            if (tid < NB) sh.p.offs[tid] += t;
            __syncthreads();
        }
        if (tid < NB) {
            int e = sh.p.offs[tid] - sh.p.hist[tid];   // exclusive
            sh.p.offs[tid] = e;
            sh.p.cur[tid] = e;
            blk_offs[pid * (NB + 1) + tid] = e;        // dense table write
        }
        if (tid == 0) blk_offs[pid * (NB + 1) + NB] = m;
        __syncthreads();

        // LDS counting-sort scatter (bucket-grouped)
        for (int i = tid; i < m; i += 1024) {
            int b = sh.p.bkt[i];
            int pos = atomicAdd(&sh.p.cur[b], 1);
            sh.p.srt[pos] = sh.p.vals[i];
        }
        __syncthreads();

        // fully coalesced sequential writeout (non-temporal: read-once data)
        unsigned* __restrict__ dst = bsorted + (size_t)pid * per4;
        for (int i = tid; i < m; i += 1024)
            __builtin_nontemporal_store(sh.p.srt[i], dst + i);
    } else {
        // ---------- transform: y = bf16(x @ W), MFMA, 16 waves ----------
        const int lane = tid & 63;
        const int w    = tid >> 6;            // 0..15
        const int l15  = lane & 15;
        const int l4   = lane >> 4;
        const int tb   = blockIdx.x >> 1;

        if (tb == 0 && tid < 8)   // zero row at index N_NODES
            ((uint4*)(y + (size_t)N_NODES * DIM))[tid] = make_uint4(0, 0, 0, 0);

        bf16x8 bfrag[4][2];
#pragma unroll
        for (int ct = 0; ct < 4; ++ct)
#pragma unroll
            for (int kt = 0; kt < 2; ++kt)
#pragma unroll
                for (int j = 0; j < 8; ++j) {
                    int k = kt * 32 + l4 * 8 + j;
                    int c = ct * 16 + l15;
                    bfrag[ct][kt][j] = (short)f2bf(W[k * DIM + c]);
                }

        ushort* myl = sh.t + w * (16 * 72);
        const int gw = tb * 16 + w;
        const int nw = NT * 16;

        for (int rt = gw; rt < N_TILES; rt += nw) {
            const float* xt = x + (size_t)rt * 16 * DIM;

            f32x4 zero = {0.f, 0.f, 0.f, 0.f};
            f32x4 acc0 = zero, acc1 = zero, acc2 = zero, acc3 = zero;
#pragma unroll
            for (int kt = 0; kt < 2; ++kt) {
                const float* ap = xt + (size_t)l15 * DIM + kt * 32 + l4 * 8;
                float4 p0 = *(const float4*)(ap);
                float4 p1 = *(const float4*)(ap + 4);
                bf16x8 afrag;
                afrag[0] = (short)f2bf(p0.x); afrag[1] = (short)f2bf(p0.y);
                afrag[2] = (short)f2bf(p0.z); afrag[3] = (short)f2bf(p0.w);
                afrag[4] = (short)f2bf(p1.x); afrag[5] = (short)f2bf(p1.y);
                afrag[6] = (short)f2bf(p1.z); afrag[7] = (short)f2bf(p1.w);
                acc0 = __builtin_amdgcn_mfma_f32_16x16x32_bf16(afrag, bfrag[0][kt], acc0, 0, 0, 0);
                acc1 = __builtin_amdgcn_mfma_f32_16x16x32_bf16(afrag, bfrag[1][kt], acc1, 0, 0, 0);
                acc2 = __builtin_amdgcn_mfma_f32_16x16x32_bf16(afrag, bfrag[2][kt], acc2, 0, 0, 0);
                acc3 = __builtin_amdgcn_mfma_f32_16x16x32_bf16(afrag, bfrag[3][kt], acc3, 0, 0, 0);
            }

#pragma unroll
            for (int r = 0; r < 4; ++r) {
                int mm = l4 * 4 + r;
                myl[mm * 72 +  0 + l15] = f2bf(acc0[r]);
                myl[mm * 72 + 16 + l15] = f2bf(acc1[r]);
                myl[mm * 72 + 32 + l15] = f2bf(acc2[r]);
                myl[mm * 72 + 48 + l15] = f2bf(acc3[r]);
            }
            int rr = lane >> 2, q = lane & 3;
            const uint4* src = (const uint4*)(myl + rr * 72 + q * 16);
            uint4 d0 = src[0];
            uint4 d1 = src[1];
            ushort* dst = y + ((size_t)(rt * 16 + rr)) * DIM + q * 16;
            *(uint4*)(dst)     = d0;
            *(uint4*)(dst + 8) = d1;
        }
    }
}

// ---- pass 2: assemble bucket (binary-search coalesced copy) +
// ----         counting sort + register gather (16 in flight) -----------
__global__ __launch_bounds__(512)
void sort_gather_kernel(const ushort* __restrict__ y,
                        const int* __restrict__ blk_offs,
                        const unsigned* __restrict__ bsorted,
                        const float* __restrict__ bias,
                        float* __restrict__ out, int per4) {
    __shared__ unsigned vals[BC];      // 8 KB assembled entries
    __shared__ unsigned sorted[BC];    // 8 KB sorted src indices
    __shared__ int lens[NP];
    __shared__ int starts[NP];         // inclusive prefix of lens
    __shared__ int losh[NP];
    __shared__ int h[BN];
    __shared__ int tmp[BN];
    __shared__ int offs[BN + 1];
    __shared__ int cur[BN];
    __shared__ int cnt_sh;

    const int tid = threadIdx.x;     // 512 threads
    const int b = blockIdx.x;

    // stage A: per-block run table for this bucket + scan of lengths
    if (tid < NP) {
        const int* po = blk_offs + tid * (NB + 1);
        int lo = po[b];
        int len = po[b + 1] - lo;
        losh[tid] = lo;
        lens[tid] = len;
        starts[tid] = len;
    }
    __syncthreads();
    for (int o = 1; o < NP; o <<= 1) {
        int t = 0;
        if (tid < NP && tid >= o) t = starts[tid - o];
        __syncthreads();
        if (tid < NP) starts[tid] += t;
        __syncthreads();
    }
    if (tid == NP - 1) cnt_sh = starts[NP - 1];
    __syncthreads();
    int cnt = cnt_sh;
    if (cnt > BC) cnt = BC;

    // stage B: cooperative copy — each output index finds its run via
    // 8-step LDS binary search; within-run reads are consecutive.
    for (int p = tid; p < cnt; p += 512) {
        int loi = 0, hii = NP - 1;
#pragma unroll
        for (int s = 0; s < 8; ++s) {
            int mid = (loi + hii) >> 1;
            if (starts[mid] > p) hii = mid; else loi = mid + 1;
        }
        int r = loi;
        int local = p - (starts[r] - lens[r]);
        vals[p] = __builtin_nontemporal_load(
            bsorted + (size_t)r * per4 + losh[r] + local);
    }

    // stage C: counting sort by local node id
    for (int i = tid; i < BN; i += 512) h[i] = 0;
    __syncthreads();
    for (int i = tid; i < cnt; i += 512) atomicAdd(&h[vals[i] >> 20], 1);
    __syncthreads();

    if (tid < BN) tmp[tid] = h[tid];
    __syncthreads();
    for (int o = 1; o < BN; o <<= 1) {
        int t = 0;
        if (tid < BN && tid >= o) t = tmp[tid - o];
        __syncthreads();
        if (tid < BN) tmp[tid] += t;
        __syncthreads();
    }
    if (tid < BN) {
        int e = tmp[tid] - h[tid];
        offs[tid] = e;
        cur[tid] = e;
    }
    if (tid == 0) offs[BN] = cnt;
    __syncthreads();

    for (int i = tid; i < cnt; i += 512) {
        unsigned v = vals[i];
        int pos = atomicAdd(&cur[v >> 20], 1);
        sorted[pos] = v & 0xFFFFFu;
    }
    __syncthreads();

    // stage D: register gather, 16 rows in flight (avg degree 12.5 ->
    // one latency round per node), non-temporal out store.
    const int grp = tid >> 4;        // 32 groups of 16 lanes
    const int f = tid & 15;
    const uint2* __restrict__ y2 = (const uint2*)y;
    const int node0 = b * BN;
    float4 bb = ((const float4*)bias)[f];

    for (int r = grp; r < BN; r += 32) {
        int nd = node0 + r;
        if (nd >= N_NODES) break;
        int s0i = offs[r], e0i = offs[r + 1];
        float a0 = 0.f, a1 = 0.f, a2 = 0.f, a3 = 0.f;
        for (int i = s0i; i < e0i; i += 16) {
            int idx[16];
#pragma unroll
            for (int k = 0; k < 16; ++k)
                idx[k] = (i + k < e0i) ? (int)sorted[i + k] : N_NODES;
#pragma unroll
            for (int k = 0; k < 16; ++k) {
                uint2 v = y2[(size_t)idx[k] * 16 + f];
                a0 += __uint_as_float(v.x << 16);
                a1 += __uint_as_float(v.x & 0xffff0000u);
                a2 += __uint_as_float(v.y << 16);
                a3 += __uint_as_float(v.y & 0xffff0000u);
            }
        }
        f32x4 o = { a0 + bb.x, a1 + bb.y, a2 + bb.z, a3 + bb.w };
        __builtin_nontemporal_store(o, (f32x4*)(out + (size_t)nd * DIM + f * 4));
    }
}

// ---- Launch ------------------------------------------------------------

extern "C" void kernel_launch(void* const* d_in, const int* in_sizes, int n_in,
                              void* d_out, int out_size, void* d_ws, size_t ws_size,
                              hipStream_t stream) {
    const float* x        = (const float*)d_in[0];
    const int*   edge_src = (const int*)d_in[1];
    const int*   edge_dst = (const int*)d_in[2];
    const float* W        = (const float*)d_in[3];
    const float* b        = (const float*)d_in[4];
    float* out = (float*)d_out;

    const int E = in_sizes[1];
    int per4 = (((E + NP - 1) / NP) + 3) & ~3;   // 4884 for E=1.25M
    if (per4 > CHUNK_P) per4 = CHUNK_P;          // safety (not hit here)

    // ws layout: y[(N+1)*64] bf16 (12.8 MB) | bsorted[NP*CHUNK_P] (5.05 MB)
    //            | blk_offs[NP*(NB+1)] (0.80 MB)   -- no memset needed
    ushort*   y        = (ushort*)d_ws;
    unsigned* bsorted  = (unsigned*)(y + (size_t)(N_NODES + 1) * DIM);
    int*      blk_offs = (int*)(bsorted + (size_t)NP * CHUNK_P);

    prep_kernel<<<NP + NT, 1024, 0, stream>>>(x, W, edge_src, edge_dst,
                                              blk_offs, bsorted, y, E, per4);
    sort_gather_kernel<<<NB, 512, 0, stream>>>(y, blk_offs, bsorted, b, out,
                                               per4);
}

// Round 21
// 59.965 us; speedup vs baseline: 1.0024x; 1.0024x over previous
//
#include <hip/hip_runtime.h>

#define N_NODES 100000
#define DIM 64
#define N_TILES (N_NODES / 16)   // 6250 row-tiles of 16

#define BSHIFT 7
#define BN 128                         // nodes per bucket
#define NB ((N_NODES + BN - 1) / BN)   // 782 buckets
#define BC 2048                        // bucket capacity (mean 1598, ~11 sigma)

#define NP 256                         // partition blocks (even)
#define NT 256                         // transform blocks (odd)
#define CHUNK_P 4928                   // >= per = ceil(E/NP) rounded to x4

using bf16x8 = __attribute__((ext_vector_type(8))) short;
using f32x4  = __attribute__((ext_vector_type(4))) float;

__device__ __forceinline__ unsigned short f2bf(float f) {
    unsigned u = __float_as_uint(f);
    unsigned r = u + 0x7FFFu + ((u >> 16) & 1u);
    return (unsigned short)(r >> 16);
}

union PrepShared {
    struct {
        unsigned vals[CHUNK_P];        // 19.7 KB packed entries
        unsigned srt[CHUNK_P];         // 19.7 KB bucket-sorted entries
        unsigned short bkt[CHUNK_P];   // 9.9 KB bucket ids
        int hist[NB];
        int offs[NB];
        int cur[NB];
    } p;                               // ~58.7 KB
    ushort t[16 * 16 * 72];            // 36.9 KB
};                                      // 2 blocks/CU: 117 KB <= 160 KB

// ---- pass 1: even blocks = partition (block-local counting sort,
// ----         dense writeout + TRANSPOSED offset table [NB+1][NP]),
// ----         odd blocks = transform (MFMA) ----------------------------
__global__ __launch_bounds__(1024, 2)
void prep_kernel(const float* __restrict__ x,
                 const float* __restrict__ W,
                 const int* __restrict__ edge_src,
                 const int* __restrict__ edge_dst,
                 int* __restrict__ blk_offsT,     // [NB+1][NP] transposed
                 unsigned* __restrict__ bsorted,  // [NP][per4]
                 ushort* __restrict__ y, int E, int per4) {
    __shared__ PrepShared sh;
    const int tid = threadIdx.x;

    if ((blockIdx.x & 1) == 0) {
        // ---------- partition -------------------------------------------
        const int pid = blockIdx.x >> 1;
        const int e0 = pid * per4;
        int m = E - e0;
        if (m < 0) m = 0;
        if (m > per4) m = per4;

        for (int i = tid; i < NB; i += 1024) sh.p.hist[i] = 0;
        __syncthreads();

        // load + pack + histogram (int4: 4 edges/thread/iter)
        {
            const int G = m >> 2;
            const int4* __restrict__ d4p = (const int4*)(edge_dst + e0);
            const int4* __restrict__ s4p = (const int4*)(edge_src + e0);
            for (int g = tid; g < G; g += 1024) {
                int4 d = d4p[g];
                int4 s = s4p[g];
                uint4 v;
                v.x = ((unsigned)(d.x & (BN - 1)) << 20) | (unsigned)s.x;
                v.y = ((unsigned)(d.y & (BN - 1)) << 20) | (unsigned)s.y;
                v.z = ((unsigned)(d.z & (BN - 1)) << 20) | (unsigned)s.z;
                v.w = ((unsigned)(d.w & (BN - 1)) << 20) | (unsigned)s.w;
                *(uint4*)(sh.p.vals + (g << 2)) = v;
                ushort4 bk;
                bk.x = (unsigned short)(d.x >> BSHIFT);
                bk.y = (unsigned short)(d.y >> BSHIFT);
                bk.z = (unsigned short)(d.z >> BSHIFT);
                bk.w = (unsigned short)(d.w >> BSHIFT);
                *(ushort4*)(sh.p.bkt + (g << 2)) = bk;
                atomicAdd(&sh.p.hist[bk.x], 1);
                atomicAdd(&sh.p.hist[bk.y], 1);
                atomicAdd(&sh.p.hist[bk.z], 1);
                atomicAdd(&sh.p.hist[bk.w], 1);
            }
            for (int i = (G << 2) + tid; i < m; i += 1024) {
                int d = edge_dst[e0 + i];
                int s = edge_src[e0 + i];
                int b = d >> BSHIFT;
                sh.p.vals[i] = ((unsigned)(d & (BN - 1)) << 20) | (unsigned)s;
                sh.p.bkt[i] = (unsigned short)b;
                atomicAdd(&sh.p.hist[b], 1);
            }
        }
        __syncthreads();

        // exclusive scan of hist over NB (Hillis-Steele, 10 rounds)
        if (tid < NB) sh.p.offs[tid] = sh.p.hist[tid];
        __syncthreads();
        for (int o = 1; o < NB; o <<= 1) {
            int t = 0;
            if (tid < NB && tid >= o) t = sh.p.offs[tid - o];
            __syncthreads();
            if (tid < NB) sh.p.offs[tid] += t;
            __syncthreads();
        }
        if (tid < NB) {
            int e = sh.p.offs[tid] - sh.p.hist[tid];   // exclusive
            sh.p.offs[tid] = e;
            sh.p.cur[tid] = e;
            blk_offsT[tid * NP + pid] = e;   // transposed (L2 merges; 0.8MB)
        }
        if (tid == 0) blk_offsT[NB * NP + pid] = m;
        __syncthreads();

        // LDS counting-sort scatter (bucket-grouped)
        for (int i = tid; i < m; i += 1024) {
            int b = sh.p.bkt[i];
            int pos = atomicAdd(&sh.p.cur[b], 1);
            sh.p.srt[pos] = sh.p.vals[i];
        }
        __syncthreads();

        // fully coalesced sequential writeout (non-temporal: read-once data)
        unsigned* __restrict__ dst = bsorted + (size_t)pid * per4;
        for (int i = tid; i < m; i += 1024)
            __builtin_nontemporal_store(sh.p.srt[i], dst + i);
    } else {
        // ---------- transform: y = bf16(x @ W), MFMA, 16 waves ----------
        const int lane = tid & 63;
        const int w    = tid >> 6;            // 0..15
        const int l15  = lane & 15;
        const int l4   = lane >> 4;
        const int tb   = blockIdx.x >> 1;

        if (tb == 0 && tid < 8)   // zero row at index N_NODES
            ((uint4*)(y + (size_t)N_NODES * DIM))[tid] = make_uint4(0, 0, 0, 0);

        bf16x8 bfrag[4][2];
#pragma unroll
        for (int ct = 0; ct < 4; ++ct)
#pragma unroll
            for (int kt = 0; kt < 2; ++kt)
#pragma unroll
                for (int j = 0; j < 8; ++j) {
                    int k = kt * 32 + l4 * 8 + j;
                    int c = ct * 16 + l15;
                    bfrag[ct][kt][j] = (short)f2bf(W[k * DIM + c]);
                }

        ushort* myl = sh.t + w * (16 * 72);
        const int gw = tb * 16 + w;
        const int nw = NT * 16;

        for (int rt = gw; rt < N_TILES; rt += nw) {
            const float* xt = x + (size_t)rt * 16 * DIM;

            f32x4 zero = {0.f, 0.f, 0.f, 0.f};
            f32x4 acc0 = zero, acc1 = zero, acc2 = zero, acc3 = zero;
#pragma unroll
            for (int kt = 0; kt < 2; ++kt) {
                const float* ap = xt + (size_t)l15 * DIM + kt * 32 + l4 * 8;
                float4 p0 = *(const float4*)(ap);
                float4 p1 = *(const float4*)(ap + 4);
                bf16x8 afrag;
                afrag[0] = (short)f2bf(p0.x); afrag[1] = (short)f2bf(p0.y);
                afrag[2] = (short)f2bf(p0.z); afrag[3] = (short)f2bf(p0.w);
                afrag[4] = (short)f2bf(p1.x); afrag[5] = (short)f2bf(p1.y);
                afrag[6] = (short)f2bf(p1.z); afrag[7] = (short)f2bf(p1.w);
                acc0 = __builtin_amdgcn_mfma_f32_16x16x32_bf16(afrag, bfrag[0][kt], acc0, 0, 0, 0);
                acc1 = __builtin_amdgcn_mfma_f32_16x16x32_bf16(afrag, bfrag[1][kt], acc1, 0, 0, 0);
                acc2 = __builtin_amdgcn_mfma_f32_16x16x32_bf16(afrag, bfrag[2][kt], acc2, 0, 0, 0);
                acc3 = __builtin_amdgcn_mfma_f32_16x16x32_bf16(afrag, bfrag[3][kt], acc3, 0, 0, 0);
            }

#pragma unroll
            for (int r = 0; r < 4; ++r) {
                int mm = l4 * 4 + r;
                myl[mm * 72 +  0 + l15] = f2bf(acc0[r]);
                myl[mm * 72 + 16 + l15] = f2bf(acc1[r]);
                myl[mm * 72 + 32 + l15] = f2bf(acc2[r]);
                myl[mm * 72 + 48 + l15] = f2bf(acc3[r]);
            }
            int rr = lane >> 2, q = lane & 3;
            const uint4* src = (const uint4*)(myl + rr * 72 + q * 16);
            uint4 d0 = src[0];
            uint4 d1 = src[1];
            ushort* dst = y + ((size_t)(rt * 16 + rr)) * DIM + q * 16;
            *(uint4*)(dst)     = d0;
            *(uint4*)(dst + 8) = d1;
        }
    }
}

// ---- pass 2: assemble bucket (coalesced offset reads + binary-search
// ----         copy) + counting sort + register gather (16 in flight) ---
__global__ __launch_bounds__(512)
void sort_gather_kernel(const ushort* __restrict__ y,
                        const int* __restrict__ blk_offsT,
                        const unsigned* __restrict__ bsorted,
                        const float* __restrict__ bias,
                        float* __restrict__ out, int per4) {
    __shared__ unsigned vals[BC];      // 8 KB assembled entries
    __shared__ unsigned sorted[BC];    // 8 KB sorted src indices
    __shared__ int lens[NP];
    __shared__ int starts[NP];         // inclusive prefix of lens
    __shared__ int losh[NP];
    __shared__ int h[BN];
    __shared__ int tmp[BN];
    __shared__ int offs[BN + 1];
    __shared__ int cur[BN];
    __shared__ int cnt_sh;

    const int tid = threadIdx.x;     // 512 threads
    const int b = blockIdx.x;

    // stage A: transposed table -> two contiguous coalesced 1KB reads
    if (tid < NP) {
        int lo  = blk_offsT[b * NP + tid];
        int nxt = blk_offsT[(b + 1) * NP + tid];
        int len = nxt - lo;
        losh[tid] = lo;
        lens[tid] = len;
        starts[tid] = len;
    }
    __syncthreads();
    for (int o = 1; o < NP; o <<= 1) {
        int t = 0;
        if (tid < NP && tid >= o) t = starts[tid - o];
        __syncthreads();
        if (tid < NP) starts[tid] += t;
        __syncthreads();
    }
    if (tid == NP - 1) cnt_sh = starts[NP - 1];
    __syncthreads();
    int cnt = cnt_sh;
    if (cnt > BC) cnt = BC;

    // stage B: cooperative copy — each output index finds its run via
    // 8-step LDS binary search; within-run reads are consecutive.
    for (int p = tid; p < cnt; p += 512) {
        int loi = 0, hii = NP - 1;
#pragma unroll
        for (int s = 0; s < 8; ++s) {
            int mid = (loi + hii) >> 1;
            if (starts[mid] > p) hii = mid; else loi = mid + 1;
        }
        int r = loi;
        int local = p - (starts[r] - lens[r]);
        vals[p] = __builtin_nontemporal_load(
            bsorted + (size_t)r * per4 + losh[r] + local);
    }

    // stage C: counting sort by local node id
    for (int i = tid; i < BN; i += 512) h[i] = 0;
    __syncthreads();
    for (int i = tid; i < cnt; i += 512) atomicAdd(&h[vals[i] >> 20], 1);
    __syncthreads();

    if (tid < BN) tmp[tid] = h[tid];
    __syncthreads();
    for (int o = 1; o < BN; o <<= 1) {
        int t = 0;
        if (tid < BN && tid >= o) t = tmp[tid - o];
        __syncthreads();
        if (tid < BN) tmp[tid] += t;
        __syncthreads();
    }
    if (tid < BN) {
        int e = tmp[tid] - h[tid];
        offs[tid] = e;
        cur[tid] = e;
    }
    if (tid == 0) offs[BN] = cnt;
    __syncthreads();

    for (int i = tid; i < cnt; i += 512) {
        unsigned v = vals[i];
        int pos = atomicAdd(&cur[v >> 20], 1);
        sorted[pos] = v & 0xFFFFFu;
    }
    __syncthreads();

    // stage D: register gather, 16 rows in flight, NT out store.
    const int grp = tid >> 4;        // 32 groups of 16 lanes
    const int f = tid & 15;
    const uint2* __restrict__ y2 = (const uint2*)y;
    const int node0 = b * BN;
    float4 bb = ((const float4*)bias)[f];

    for (int r = grp; r < BN; r += 32) {
        int nd = node0 + r;
        if (nd >= N_NODES) break;
        int s0i = offs[r], e0i = offs[r + 1];
        float a0 = 0.f, a1 = 0.f, a2 = 0.f, a3 = 0.f;
        for (int i = s0i; i < e0i; i += 16) {
            int idx[16];
#pragma unroll
            for (int k = 0; k < 16; ++k)
                idx[k] = (i + k < e0i) ? (int)sorted[i + k] : N_NODES;
#pragma unroll
            for (int k = 0; k < 16; ++k) {
                uint2 v = y2[(size_t)idx[k] * 16 + f];
                a0 += __uint_as_float(v.x << 16);
                a1 += __uint_as_float(v.x & 0xffff0000u);
                a2 += __uint_as_float(v.y << 16);
                a3 += __uint_as_float(v.y & 0xffff0000u);
            }
        }
        f32x4 o = { a0 + bb.x, a1 + bb.y, a2 + bb.z, a3 + bb.w };
        __builtin_nontemporal_store(o, (f32x4*)(out + (size_t)nd * DIM + f * 4));
    }
}

// ---- Launch ------------------------------------------------------------

extern "C" void kernel_launch(void* const* d_in, const int* in_sizes, int n_in,
                              void* d_out, int out_size, void* d_ws, size_t ws_size,
                              hipStream_t stream) {
    const float* x        = (const float*)d_in[0];
    const int*   edge_src = (const int*)d_in[1];
    const int*   edge_dst = (const int*)d_in[2];
    const float* W        = (const float*)d_in[3];
    const float* b        = (const float*)d_in[4];
    float* out = (float*)d_out;

    const int E = in_sizes[1];
    int per4 = (((E + NP - 1) / NP) + 3) & ~3;   // 4884 for E=1.25M
    if (per4 > CHUNK_P) per4 = CHUNK_P;          // safety (not hit here)

    // ws layout: y[(N+1)*64] bf16 (12.8 MB) | bsorted[NP*CHUNK_P] (5.05 MB)
    //            | blk_offsT[(NB+1)*NP] (0.80 MB)  -- no memset needed
    ushort*   y         = (ushort*)d_ws;
    unsigned* bsorted   = (unsigned*)(y + (size_t)(N_NODES + 1) * DIM);
    int*      blk_offsT = (int*)(bsorted + (size_t)NP * CHUNK_P);

    prep_kernel<<<NP + NT, 1024, 0, stream>>>(x, W, edge_src, edge_dst,
                                              blk_offsT, bsorted, y, E, per4);
    sort_gather_kernel<<<NB, 512, 0, stream>>>(y, blk_offsT, bsorted, b, out,
                                               per4);
}

// Round 22
// 58.808 us; speedup vs baseline: 1.0222x; 1.0197x over previous
//
#include <hip/hip_runtime.h>

#define N_NODES 100000
#define DIM 64
#define N_TILES (N_NODES / 16)   // 6250 row-tiles of 16

#define BSHIFT 7
#define BN 128                         // nodes per bucket
#define NB ((N_NODES + BN - 1) / BN)   // 782 buckets
#define BC 2048                        // bucket capacity (mean 1598, ~11 sigma)

#define NP 256                         // partition blocks (even)
#define NT 256                         // transform blocks (odd)
#define CHUNK_P 4928                   // >= per = ceil(E/NP) rounded to x4

using bf16x8 = __attribute__((ext_vector_type(8))) short;
using f32x4  = __attribute__((ext_vector_type(4))) float;

__device__ __forceinline__ unsigned short f2bf(float f) {
    unsigned u = __float_as_uint(f);
    unsigned r = u + 0x7FFFu + ((u >> 16) & 1u);
    return (unsigned short)(r >> 16);
}

// wave-inclusive scan of v across 64 lanes
__device__ __forceinline__ int wave_iscan(int v, int lane) {
#pragma unroll
    for (int off = 1; off < 64; off <<= 1) {
        int t = __shfl_up(v, off, 64);
        if (lane >= off) v += t;
    }
    return v;
}

union PrepShared {
    struct {
        unsigned vals[CHUNK_P];        // 19.7 KB packed entries
        unsigned srt[CHUNK_P];         // 19.7 KB bucket-sorted entries
        unsigned short bkt[CHUNK_P];   // 9.9 KB bucket ids
        int hist[NB];
        int cur[NB];
        int ws[16];
    } p;                               // ~55.7 KB
    ushort t[16 * 16 * 72];            // 36.9 KB
};                                      // 2 blocks/CU fits LDS

// ---- pass 1: even blocks = partition (block-local counting sort,
// ----         dense writeout + TRANSPOSED offset table [NB+1][NP]),
// ----         odd blocks = transform (MFMA) ----------------------------
__global__ __launch_bounds__(1024, 2)
void prep_kernel(const float* __restrict__ x,
                 const float* __restrict__ W,
                 const int* __restrict__ edge_src,
                 const int* __restrict__ edge_dst,
                 int* __restrict__ blk_offsT,     // [NB+1][NP] transposed
                 unsigned* __restrict__ bsorted,  // [NP][per4]
                 ushort* __restrict__ y, int E, int per4) {
    __shared__ PrepShared sh;
    const int tid = threadIdx.x;

    if ((blockIdx.x & 1) == 0) {
        // ---------- partition -------------------------------------------
        const int pid = blockIdx.x >> 1;
        const int e0 = pid * per4;
        int m = E - e0;
        if (m < 0) m = 0;
        if (m > per4) m = per4;

        for (int i = tid; i < NB; i += 1024) sh.p.hist[i] = 0;
        __syncthreads();

        // load + pack + histogram (int4: 4 edges/thread/iter)
        {
            const int G = m >> 2;
            const int4* __restrict__ d4p = (const int4*)(edge_dst + e0);
            const int4* __restrict__ s4p = (const int4*)(edge_src + e0);
            for (int g = tid; g < G; g += 1024) {
                int4 d = d4p[g];
                int4 s = s4p[g];
                uint4 v;
                v.x = ((unsigned)(d.x & (BN - 1)) << 20) | (unsigned)s.x;
                v.y = ((unsigned)(d.y & (BN - 1)) << 20) | (unsigned)s.y;
                v.z = ((unsigned)(d.z & (BN - 1)) << 20) | (unsigned)s.z;
                v.w = ((unsigned)(d.w & (BN - 1)) << 20) | (unsigned)s.w;
                *(uint4*)(sh.p.vals + (g << 2)) = v;
                ushort4 bk;
                bk.x = (unsigned short)(d.x >> BSHIFT);
                bk.y = (unsigned short)(d.y >> BSHIFT);
                bk.z = (unsigned short)(d.z >> BSHIFT);
                bk.w = (unsigned short)(d.w >> BSHIFT);
                *(ushort4*)(sh.p.bkt + (g << 2)) = bk;
                atomicAdd(&sh.p.hist[bk.x], 1);
                atomicAdd(&sh.p.hist[bk.y], 1);
                atomicAdd(&sh.p.hist[bk.z], 1);
                atomicAdd(&sh.p.hist[bk.w], 1);
            }
            for (int i = (G << 2) + tid; i < m; i += 1024) {
                int d = edge_dst[e0 + i];
                int s = edge_src[e0 + i];
                int b = d >> BSHIFT;
                sh.p.vals[i] = ((unsigned)(d & (BN - 1)) << 20) | (unsigned)s;
                sh.p.bkt[i] = (unsigned short)b;
                atomicAdd(&sh.p.hist[b], 1);
            }
        }
        __syncthreads();

        // exclusive scan of hist over NB: wave shfl scan (3 barriers)
        {
            const int lane = tid & 63;
            int hv = (tid < NB) ? sh.p.hist[tid] : 0;
            int v = wave_iscan(hv, lane);
            if (lane == 63) sh.p.ws[tid >> 6] = v;
            __syncthreads();
            if (tid == 0) {
                int run = 0;
#pragma unroll
                for (int i = 0; i < 16; ++i) {
                    int t = sh.p.ws[i];
                    sh.p.ws[i] = run;
                    run += t;
                }
            }
            __syncthreads();
            if (tid < NB) {
                int inc = v + sh.p.ws[tid >> 6];
                int e = inc - hv;                  // exclusive
                sh.p.cur[tid] = e;
                blk_offsT[tid * NP + pid] = e;     // transposed table
            }
            if (tid == 0) blk_offsT[NB * NP + pid] = m;
        }
        __syncthreads();

        // LDS counting-sort scatter (bucket-grouped)
        for (int i = tid; i < m; i += 1024) {
            int b = sh.p.bkt[i];
            int pos = atomicAdd(&sh.p.cur[b], 1);
            sh.p.srt[pos] = sh.p.vals[i];
        }
        __syncthreads();

        // fully coalesced sequential writeout (non-temporal: read-once data)
        unsigned* __restrict__ dst = bsorted + (size_t)pid * per4;
        for (int i = tid; i < m; i += 1024)
            __builtin_nontemporal_store(sh.p.srt[i], dst + i);
    } else {
        // ---------- transform: y = bf16(x @ W), MFMA, 16 waves ----------
        const int lane = tid & 63;
        const int w    = tid >> 6;            // 0..15
        const int l15  = lane & 15;
        const int l4   = lane >> 4;
        const int tb   = blockIdx.x >> 1;

        if (tb == 0 && tid < 8)   // zero row at index N_NODES
            ((uint4*)(y + (size_t)N_NODES * DIM))[tid] = make_uint4(0, 0, 0, 0);

        bf16x8 bfrag[4][2];
#pragma unroll
        for (int ct = 0; ct < 4; ++ct)
#pragma unroll
            for (int kt = 0; kt < 2; ++kt)
#pragma unroll
                for (int j = 0; j < 8; ++j) {
                    int k = kt * 32 + l4 * 8 + j;
                    int c = ct * 16 + l15;
                    bfrag[ct][kt][j] = (short)f2bf(W[k * DIM + c]);
                }

        ushort* myl = sh.t + w * (16 * 72);
        const int gw = tb * 16 + w;
        const int nw = NT * 16;

        for (int rt = gw; rt < N_TILES; rt += nw) {
            const float* xt = x + (size_t)rt * 16 * DIM;

            f32x4 zero = {0.f, 0.f, 0.f, 0.f};
            f32x4 acc0 = zero, acc1 = zero, acc2 = zero, acc3 = zero;
#pragma unroll
            for (int kt = 0; kt < 2; ++kt) {
                const float* ap = xt + (size_t)l15 * DIM + kt * 32 + l4 * 8;
                float4 p0 = *(const float4*)(ap);
                float4 p1 = *(const float4*)(ap + 4);
                bf16x8 afrag;
                afrag[0] = (short)f2bf(p0.x); afrag[1] = (short)f2bf(p0.y);
                afrag[2] = (short)f2bf(p0.z); afrag[3] = (short)f2bf(p0.w);
                afrag[4] = (short)f2bf(p1.x); afrag[5] = (short)f2bf(p1.y);
                afrag[6] = (short)f2bf(p1.z); afrag[7] = (short)f2bf(p1.w);
                acc0 = __builtin_amdgcn_mfma_f32_16x16x32_bf16(afrag, bfrag[0][kt], acc0, 0, 0, 0);
                acc1 = __builtin_amdgcn_mfma_f32_16x16x32_bf16(afrag, bfrag[1][kt], acc1, 0, 0, 0);
                acc2 = __builtin_amdgcn_mfma_f32_16x16x32_bf16(afrag, bfrag[2][kt], acc2, 0, 0, 0);
                acc3 = __builtin_amdgcn_mfma_f32_16x16x32_bf16(afrag, bfrag[3][kt], acc3, 0, 0, 0);
            }

#pragma unroll
            for (int r = 0; r < 4; ++r) {
                int mm = l4 * 4 + r;
                myl[mm * 72 +  0 + l15] = f2bf(acc0[r]);
                myl[mm * 72 + 16 + l15] = f2bf(acc1[r]);
                myl[mm * 72 + 32 + l15] = f2bf(acc2[r]);
                myl[mm * 72 + 48 + l15] = f2bf(acc3[r]);
            }
            int rr = lane >> 2, q = lane & 3;
            const uint4* src = (const uint4*)(myl + rr * 72 + q * 16);
            uint4 d0 = src[0];
            uint4 d1 = src[1];
            ushort* dst = y + ((size_t)(rt * 16 + rr)) * DIM + q * 16;
            *(uint4*)(dst)     = d0;
            *(uint4*)(dst + 8) = d1;
        }
    }
}

// ---- pass 2: assemble bucket + counting sort (shfl scans, few barriers)
// ----         + register gather (16 in flight) -------------------------
__global__ __launch_bounds__(512)
void sort_gather_kernel(const ushort* __restrict__ y,
                        const int* __restrict__ blk_offsT,
                        const unsigned* __restrict__ bsorted,
                        const float* __restrict__ bias,
                        float* __restrict__ out, int per4) {
    __shared__ unsigned vals[BC];      // 8 KB assembled entries
    __shared__ unsigned sorted[BC];    // 8 KB sorted src indices
    __shared__ int lens[NP];
    __shared__ int starts[NP];         // inclusive prefix of lens
    __shared__ int losh[NP];
    __shared__ int h[BN];
    __shared__ int offs[BN + 1];
    __shared__ int cur[BN];
    __shared__ int ws[8];
    __shared__ int cnt_sh;

    const int tid = threadIdx.x;     // 512 threads
    const int lane = tid & 63;
    const int b = blockIdx.x;

    // stage A: transposed table -> coalesced reads; shfl scan of lens
    {
        int len = 0;
        if (tid < NP) {
            int lo  = blk_offsT[b * NP + tid];
            int nxt = blk_offsT[(b + 1) * NP + tid];
            len = nxt - lo;
            losh[tid] = lo;
            lens[tid] = len;
        }
        int v = wave_iscan(len, lane);
        if (lane == 63 && tid < NP) ws[tid >> 6] = v;
        __syncthreads();
        if (tid == 0) {
            int run = 0;
#pragma unroll
            for (int i = 0; i < NP / 64; ++i) {
                int t = ws[i];
                ws[i] = run;
                run += t;
            }
            cnt_sh = run;   // will be overwritten below with full sum
        }
        __syncthreads();
        if (tid < NP) {
            int inc = v + ws[tid >> 6];
            starts[tid] = inc;
            if (tid == NP - 1) cnt_sh = inc;
        }
    }
    __syncthreads();
    int cnt = cnt_sh;
    if (cnt > BC) cnt = BC;

    // stage B: cooperative copy — binary search on starts; within-run
    // reads are consecutive.
    for (int p = tid; p < cnt; p += 512) {
        int loi = 0, hii = NP - 1;
#pragma unroll
        for (int s = 0; s < 8; ++s) {
            int mid = (loi + hii) >> 1;
            if (starts[mid] > p) hii = mid; else loi = mid + 1;
        }
        int r = loi;
        int local = p - (starts[r] - lens[r]);
        vals[p] = __builtin_nontemporal_load(
            bsorted + (size_t)r * per4 + losh[r] + local);
    }

    // stage C: counting sort by local node id (shfl scan)
    for (int i = tid; i < BN; i += 512) h[i] = 0;
    __syncthreads();
    for (int i = tid; i < cnt; i += 512) atomicAdd(&h[vals[i] >> 20], 1);
    __syncthreads();

    {
        int hv = (tid < BN) ? h[tid] : 0;
        int v = wave_iscan(hv, lane);
        if (lane == 63 && tid < BN) ws[tid >> 6] = v;
        __syncthreads();
        if (tid == 0) {
            int t0 = ws[0];
            ws[0] = 0;
            ws[1] = t0;
        }
        __syncthreads();
        if (tid < BN) {
            int inc = v + ws[tid >> 6];
            int e = inc - hv;                 // exclusive
            offs[tid] = e;
            cur[tid] = e;
        }
        if (tid == 0) offs[BN] = cnt;
    }
    __syncthreads();

    for (int i = tid; i < cnt; i += 512) {
        unsigned v = vals[i];
        int pos = atomicAdd(&cur[v >> 20], 1);
        sorted[pos] = v & 0xFFFFFu;
    }
    __syncthreads();

    // stage D: register gather, 16 rows in flight, NT out store.
    const int grp = tid >> 4;        // 32 groups of 16 lanes
    const int f = tid & 15;
    const uint2* __restrict__ y2 = (const uint2*)y;
    const int node0 = b * BN;
    float4 bb = ((const float4*)bias)[f];

    for (int r = grp; r < BN; r += 32) {
        int nd = node0 + r;
        if (nd >= N_NODES) break;
        int s0i = offs[r], e0i = offs[r + 1];
        float a0 = 0.f, a1 = 0.f, a2 = 0.f, a3 = 0.f;
        for (int i = s0i; i < e0i; i += 16) {
            int idx[16];
#pragma unroll
            for (int k = 0; k < 16; ++k)
                idx[k] = (i + k < e0i) ? (int)sorted[i + k] : N_NODES;
#pragma unroll
            for (int k = 0; k < 16; ++k) {
                uint2 v = y2[(size_t)idx[k] * 16 + f];
                a0 += __uint_as_float(v.x << 16);
                a1 += __uint_as_float(v.x & 0xffff0000u);
                a2 += __uint_as_float(v.y << 16);
                a3 += __uint_as_float(v.y & 0xffff0000u);
            }
        }
        f32x4 o = { a0 + bb.x, a1 + bb.y, a2 + bb.z, a3 + bb.w };
        __builtin_nontemporal_store(o, (f32x4*)(out + (size_t)nd * DIM + f * 4));
    }
}

// ---- Launch ------------------------------------------------------------

extern "C" void kernel_launch(void* const* d_in, const int* in_sizes, int n_in,
                              void* d_out, int out_size, void* d_ws, size_t ws_size,
                              hipStream_t stream) {
    const float* x        = (const float*)d_in[0];
    const int*   edge_src = (const int*)d_in[1];
    const int*   edge_dst = (const int*)d_in[2];
    const float* W        = (const float*)d_in[3];
    const float* b        = (const float*)d_in[4];
    float* out = (float*)d_out;

    const int E = in_sizes[1];
    int per4 = (((E + NP - 1) / NP) + 3) & ~3;   // 4884 for E=1.25M
    if (per4 > CHUNK_P) per4 = CHUNK_P;          // safety (not hit here)

    // ws layout: y[(N+1)*64] bf16 (12.8 MB) | bsorted[NP*CHUNK_P] (5.05 MB)
    //            | blk_offsT[(NB+1)*NP] (0.80 MB)  -- no memset needed
    ushort*   y         = (ushort*)d_ws;
    unsigned* bsorted   = (unsigned*)(y + (size_t)(N_NODES + 1) * DIM);
    int*      blk_offsT = (int*)(bsorted + (size_t)NP * CHUNK_P);

    prep_kernel<<<NP + NT, 1024, 0, stream>>>(x, W, edge_src, edge_dst,
                                              blk_offsT, bsorted, y, E, per4);
    sort_gather_kernel<<<NB, 512, 0, stream>>>(y, blk_offsT, bsorted, b, out,
                                               per4);
}